// Round 4
// baseline (24.010 us; speedup 1.0000x reference)
//
#include <hip/hip_runtime.h>
#include <math.h>

#define B 2048
#define D 4096
#define C 1000
#define NNEG 16
#define EPS 1e-8f
#define MAXW 32  // per-wave match cap (wave covers 512 rows; E[matches] ~ 0.5)

// ws layout (floats):
//   [0..B)           ce_part   (lse - target logit, per row)
//   [B..B+C)         pos_sim   (per-class pair-sim sum)
//   [B+C..B+2C)      pos_cnt   (per-class pair count)
//   [B+2C..+NNEG)    neg_part  (relu'd sim per pair)
// Every slot fully written every call -> no zeroing, no global atomics.

__device__ __forceinline__ float wave_sum(float v) {
#pragma unroll
    for (int off = 32; off > 0; off >>= 1) v += __shfl_down(v, off, 64);
    return v;
}
__device__ __forceinline__ float wave_max(float v) {
#pragma unroll
    for (int off = 32; off > 0; off >>= 1) v = fmaxf(v, __shfl_down(v, off, 64));
    return v;
}

// Fused: blocks [0,C) per-class pair-sim; [C,C+NNEG) negative pairs;
//        [C+NNEG, ...) cross-entropy rows. xs read exactly once from HBM
//        (class pass-2 reload is L2/L3-resident).
__global__ __launch_bounds__(256) void k_main(const float* __restrict__ xs,
                                              const float* __restrict__ yp,
                                              const int* __restrict__ yt,
                                              float* __restrict__ ce_part,
                                              float* __restrict__ pos_sim,
                                              float* __restrict__ pos_cnt,
                                              float* __restrict__ neg_part) {
    __shared__ float sbuf[12];
    const int lane = threadIdx.x & 63, wid = threadIdx.x >> 6;
    const int blk = blockIdx.x;

    if (blk < C) {
        // ---- per-class:  sum_{i<j in c} sim = (||S_c||^2 - n) / 2 ----
        const int cls = blk;
        __shared__ int midx[4][MAXW];
        __shared__ int mcnt[4];
        __shared__ float ss_lds[4 * MAXW * 4];  // [slot][wid] norm partials

        // ballot-based match scan: wave w covers rows [w*512, (w+1)*512)
        int cw = 0;
#pragma unroll
        for (int chunk = 0; chunk < 8; ++chunk) {
            const int i = (wid << 9) + (chunk << 6) + lane;
            const bool m = (yt[i] == cls);
            const unsigned long long mask = __ballot(m);
            if (m) {
                int pos = cw + __popcll(mask & ((1ULL << lane) - 1));
                if (pos < MAXW) midx[wid][pos] = i;
            }
            cw += __popcll(mask);
        }
        if (lane == 0) mcnt[wid] = (cw < MAXW) ? cw : MAXW;
        __syncthreads();

        int cnt[4];
        cnt[0] = mcnt[0]; cnt[1] = mcnt[1]; cnt[2] = mcnt[2]; cnt[3] = mcnt[3];
        const int n = cnt[0] + cnt[1] + cnt[2] + cnt[3];

        // pass 1: per-row norm partials, NO block barriers (loads pipeline)
        for (int w = 0; w < 4; ++w) {
            for (int t = 0; t < cnt[w]; ++t) {
                const int i = midx[w][t];
                const float4* r = reinterpret_cast<const float4*>(xs + (size_t)i * D);
                float4 v0 = r[threadIdx.x];
                float4 v1 = r[threadIdx.x + 256];
                float4 v2 = r[threadIdx.x + 512];
                float4 v3 = r[threadIdx.x + 768];
                float ss = v0.x * v0.x + v0.y * v0.y + v0.z * v0.z + v0.w * v0.w
                         + v1.x * v1.x + v1.y * v1.y + v1.z * v1.z + v1.w * v1.w
                         + v2.x * v2.x + v2.y * v2.y + v2.z * v2.z + v2.w * v2.w
                         + v3.x * v3.x + v3.y * v3.y + v3.z * v3.z + v3.w * v3.w;
                ss = wave_sum(ss);
                if (lane == 0) ss_lds[((w * MAXW + t) << 2) + wid] = ss;
            }
        }
        __syncthreads();

        // pass 2: reload (cache-hot) scaled by inv-norm, accumulate S_c
        float4 a0 = {0, 0, 0, 0}, a1 = {0, 0, 0, 0}, a2 = {0, 0, 0, 0}, a3 = {0, 0, 0, 0};
        for (int w = 0; w < 4; ++w) {
            for (int t = 0; t < cnt[w]; ++t) {
                const int i = midx[w][t];
                const int slot = (w * MAXW + t) << 2;
                const float tot = ss_lds[slot] + ss_lds[slot + 1] + ss_lds[slot + 2] + ss_lds[slot + 3];
                const float inv = 1.0f / fmaxf(sqrtf(tot), EPS);
                const float4* r = reinterpret_cast<const float4*>(xs + (size_t)i * D);
                float4 v0 = r[threadIdx.x];
                float4 v1 = r[threadIdx.x + 256];
                float4 v2 = r[threadIdx.x + 512];
                float4 v3 = r[threadIdx.x + 768];
                a0.x = fmaf(v0.x, inv, a0.x); a0.y = fmaf(v0.y, inv, a0.y);
                a0.z = fmaf(v0.z, inv, a0.z); a0.w = fmaf(v0.w, inv, a0.w);
                a1.x = fmaf(v1.x, inv, a1.x); a1.y = fmaf(v1.y, inv, a1.y);
                a1.z = fmaf(v1.z, inv, a1.z); a1.w = fmaf(v1.w, inv, a1.w);
                a2.x = fmaf(v2.x, inv, a2.x); a2.y = fmaf(v2.y, inv, a2.y);
                a2.z = fmaf(v2.z, inv, a2.z); a2.w = fmaf(v2.w, inv, a2.w);
                a3.x = fmaf(v3.x, inv, a3.x); a3.y = fmaf(v3.y, inv, a3.y);
                a3.z = fmaf(v3.z, inv, a3.z); a3.w = fmaf(v3.w, inv, a3.w);
            }
        }
        float s2 = a0.x * a0.x + a0.y * a0.y + a0.z * a0.z + a0.w * a0.w
                 + a1.x * a1.x + a1.y * a1.y + a1.z * a1.z + a1.w * a1.w
                 + a2.x * a2.x + a2.y * a2.y + a2.z * a2.z + a2.w * a2.w
                 + a3.x * a3.x + a3.y * a3.y + a3.z * a3.z + a3.w * a3.w;
        s2 = wave_sum(s2);
        if (lane == 0) sbuf[wid] = s2;
        __syncthreads();
        if (threadIdx.x == 0) {
            float S2 = sbuf[0] + sbuf[1] + sbuf[2] + sbuf[3];
            // sum_i ||xn_i||^2 == n by construction
            pos_sim[cls] = (n >= 2) ? 0.5f * (S2 - (float)n) : 0.0f;
            pos_cnt[cls] = 0.5f * (float)n * (float)(n - 1);
        }
    } else if (blk < C + NNEG) {
        // ---- negative pair (0, j), inline norms ----
        const int j = blk - C + 1;
        const float4* r0 = reinterpret_cast<const float4*>(xs);
        const float4* rj = reinterpret_cast<const float4*>(xs + (size_t)j * D);
        float ss0 = 0.0f, ssj = 0.0f, d = 0.0f;
#pragma unroll
        for (int k = 0; k < 4; ++k) {
            float4 a = r0[threadIdx.x + k * 256];
            float4 b = rj[threadIdx.x + k * 256];
            ss0 += a.x * a.x + a.y * a.y + a.z * a.z + a.w * a.w;
            ssj += b.x * b.x + b.y * b.y + b.z * b.z + b.w * b.w;
            d = fmaf(a.x, b.x, fmaf(a.y, b.y, fmaf(a.z, b.z, fmaf(a.w, b.w, d))));
        }
        ss0 = wave_sum(ss0);
        ssj = wave_sum(ssj);
        d = wave_sum(d);
        if (lane == 0) {
            sbuf[wid] = ss0;
            sbuf[4 + wid] = ssj;
            sbuf[8 + wid] = d;
        }
        __syncthreads();
        if (threadIdx.x == 0) {
            float n0 = fmaxf(sqrtf(sbuf[0] + sbuf[1] + sbuf[2] + sbuf[3]), EPS);
            float nj = fmaxf(sqrtf(sbuf[4] + sbuf[5] + sbuf[6] + sbuf[7]), EPS);
            float dot = sbuf[8] + sbuf[9] + sbuf[10] + sbuf[11];
            neg_part[j - 1] = fmaxf(0.0f, dot / (n0 * nj));
        }
    } else {
        // ---- cross-entropy row (float4 loads: C = 250 float4) ----
        const int row = blk - C - NNEG;
        __shared__ float lds[C];
        const float4* r4 = reinterpret_cast<const float4*>(yp + (size_t)row * C);
        float4 v = {0.0f, 0.0f, 0.0f, 0.0f};
        float m = -INFINITY;
        if (threadIdx.x < 250) {
            v = r4[threadIdx.x];
            reinterpret_cast<float4*>(lds)[threadIdx.x] = v;
            m = fmaxf(fmaxf(v.x, v.y), fmaxf(v.z, v.w));
        }
        m = wave_max(m);
        if (lane == 0) sbuf[wid] = m;
        __syncthreads();
        m = fmaxf(fmaxf(sbuf[0], sbuf[1]), fmaxf(sbuf[2], sbuf[3]));
        float s = 0.0f;
        if (threadIdx.x < 250) {
            s = expf(v.x - m) + expf(v.y - m) + expf(v.z - m) + expf(v.w - m);
        }
        s = wave_sum(s);
        if (lane == 0) sbuf[4 + wid] = s;  // disjoint slots: no extra barrier needed
        __syncthreads();
        if (threadIdx.x == 0) {
            float tot = sbuf[4] + sbuf[5] + sbuf[6] + sbuf[7];
            ce_part[row] = logf(tot) + m - lds[yt[row]];
        }
    }
}

__global__ __launch_bounds__(256) void k_finalize(const float* __restrict__ ce_part,
                                                  const float* __restrict__ pos_sim,
                                                  const float* __restrict__ pos_cnt,
                                                  const float* __restrict__ neg_part,
                                                  float* __restrict__ out) {
    __shared__ float sbuf[12];
    const int lane = threadIdx.x & 63, wid = threadIdx.x >> 6;
    float s_ce = 0.0f, s_sim = 0.0f, s_cnt = 0.0f;
    for (int i = threadIdx.x; i < B; i += 256) s_ce += ce_part[i];
    for (int i = threadIdx.x; i < C; i += 256) {
        s_sim += pos_sim[i];
        s_cnt += pos_cnt[i];
    }
    float s_neg = (threadIdx.x < NNEG) ? neg_part[threadIdx.x] : 0.0f;
    s_ce = wave_sum(s_ce);
    s_sim = wave_sum(s_sim);
    s_cnt = wave_sum(s_cnt);
    s_neg = wave_sum(s_neg);
    if (lane == 0) {
        sbuf[wid] = s_ce;
        sbuf[4 + wid] = s_sim;
        sbuf[8 + wid] = s_cnt;
    }
    __syncthreads();
    if (threadIdx.x == 0) {
        float ce = (sbuf[0] + sbuf[1] + sbuf[2] + sbuf[3]) / (float)B;
        float sim = sbuf[4] + sbuf[5] + sbuf[6] + sbuf[7];
        float cnt = sbuf[8] + sbuf[9] + sbuf[10] + sbuf[11];
        float pos = (cnt > 0.0f) ? (cnt - sim) / cnt : 0.0f;
        float neg = s_neg / (float)NNEG;  // wave 0 covers lanes 0..15
        out[0] = ce + pos + neg;
    }
}

extern "C" void kernel_launch(void* const* d_in, const int* in_sizes, int n_in,
                              void* d_out, int out_size, void* d_ws, size_t ws_size,
                              hipStream_t stream) {
    const float* xs = (const float*)d_in[0];
    const float* yp = (const float*)d_in[1];
    const int* yt = (const int*)d_in[2];
    float* out = (float*)d_out;

    float* ce_part = (float*)d_ws;
    float* pos_sim = ce_part + B;
    float* pos_cnt = pos_sim + C;
    float* neg_part = pos_cnt + C;

    k_main<<<C + NNEG + B, 256, 0, stream>>>(xs, yp, yt, ce_part, pos_sim, pos_cnt, neg_part);
    k_finalize<<<1, 256, 0, stream>>>(ce_part, pos_sim, pos_cnt, neg_part, out);
}